// Round 8
// baseline (3491.080 us; speedup 1.0000x reference)
//
#include <hip/hip_runtime.h>
#include <math.h>

// Archetipes RNN scan: T=256 sequential steps, M=16 modules, H=256, I=128.
// R8: "data IS the flag". R7 post-mortem: 8.8 us/step = flag store -> LLC
// -> poll detect -> separate data fetch (2 serialized LLC round trips), plus
// 262k pollers hammering 16 flag lines (same-line LLC serialization), plus
// 25.2M LDS bank conflicts from the unpadded transpose.
// Changes:
//  1. Publish = ONE relaxed agent u64 store per (wave,step): packed
//     (fp32 hy << 32 | epoch tag). No flag array, no release store, no
//     post-publish __syncthreads (nothing to drain on the critical path).
//  2. Consumers poll their own 32 B (4 u64) of slot t directly: tag match
//     means the value is already in the register. One LLC round trip.
//     Polling spreads over 512 lines, 2 pollers/line -> no hot lines.
//  3. LDS hy double-buffer -> exactly ONE __syncthreads per step.
//  4. Transpose pad H+4: bank = (16*(lane&3)+ (lane>>2)+4k+16w)%32 -> 2-way
//     (free per m136). R7's unpadded version was 4-way, 25.2M conflicts.
// Epoch: g_epoch += T once per launch (block 0, end). base read at entry.
// Launches are stream-serialized -> replay-safe. First launch: zero-filled
// slot 0 has tag 0 == base and value 0 == correct initial state.
// Weights register/AGPR-resident (R3: one-time 33.6 MB fetch).
// outputs buffered in LDS, single flush after the loop (R7: out-store acks
// off the critical path).

#define DT_C    0.042f
#define GAMMA_C 2.7f
#define EPS_C   4.7f

constexpr int M = 16, H = 256, I = 128, T = 256;
constexpr int NROW = M * H;   // 4096
constexpr int NBLK = 256;
constexpr int NTHR = 1024;    // 16 waves
constexpr int HP   = H + 4;   // padded LDS row

typedef float f32x4 __attribute__((ext_vector_type(4)));
typedef unsigned long long u64;

// Slot s = hy after s steps, packed (value<<32 | tag), layout [s][h][m]
// (128 B per (s,h)). Written once per launch (values bitwise-identical
// across replays, tags monotone). 8.4 MB.
__device__ __align__(64) u64 g_hy[(size_t)(T + 1) * NROW];
__device__ unsigned int g_epoch;

__device__ __forceinline__ u64 pack(float v, unsigned int tag) {
  return ((u64)__float_as_uint(v) << 32) | (u64)tag;
}

__global__ __launch_bounds__(NTHR) void rnn_persistent(
    const float* __restrict__ x,      // T*I
    const float* __restrict__ wm,     // M*M*H*H
    const float* __restrict__ conn,   // M*M
    const float* __restrict__ mask,   // M
    const float* __restrict__ W_in,   // M*H*I
    const float* __restrict__ W_rec,  // M*H*H
    const float* __restrict__ bias,   // M*H
    float* __restrict__ out)          // T*M*2*H state_seq, then T*M*H fb_seq
{
  const int h    = blockIdx.x;
  const int tid  = threadIdx.x;
  const int m    = tid >> 6;      // wave = module
  const int lane = tid & 63;

  __shared__ float hy_lds[2][M * HP];   // 2 x 16.25 KB, layout [m][h]
  __shared__ float outb_hz[T][M];       // 16 KB
  __shared__ float outb_fb[T][M];       // 16 KB
  __shared__ float s_c[M * M];
  __shared__ float s_scal[M];
  __shared__ int   s_olist[M][M];
  __shared__ float s_oc[M][M];
  __shared__ int   s_ocnt[M];
  __shared__ unsigned int s_base;

  if (tid == 0)
    s_base = __hip_atomic_load(&g_epoch, __ATOMIC_RELAXED, __HIP_MEMORY_SCOPE_AGENT);
  if (tid < M * M) s_c[tid] = conn[tid];
  __syncthreads();
  if (tid < M) {
    float s = 0.f; int cnt = 0;
    for (int o = 0; o < M; ++o) {
      float c = s_c[tid * M + o];
      s += c;
      if (c != 0.f) { s_olist[tid][cnt] = o; s_oc[tid][cnt] = c; ++cnt; }
    }
    for (int k = cnt; k < M; ++k) { s_olist[tid][k] = 0; s_oc[tid][k] = 0.f; }
    s_ocnt[tid] = cnt;
    s_scal[tid] = 1.0f / fmaxf(s, 1.0f);
  }
  __syncthreads();

  const int   row   = m * H + h;
  const float maskm = mask[m];
  const float biasv = bias[row];
  const float scal  = s_scal[m];
  const int   ocnt  = s_ocnt[m];
  const unsigned int base = s_base;

  // ---- one-time: weights into registers (conn pre-applied) ----
  f32x4 wreg[M];
#pragma unroll
  for (int k = 0; k < M; ++k) {
    if (k < ocnt) {
      const int o = s_olist[m][k];
      const f32x4 wv = *reinterpret_cast<const f32x4*>(
          wm + ((size_t)(m * M + o) * H + h) * H + 4 * lane);
      wreg[k] = wv * s_oc[m][k];
    } else {
      wreg[k] = (f32x4)0.f;
    }
  }
  const f32x4  wrec = *reinterpret_cast<const f32x4*>(W_rec + (size_t)row * H + 4 * lane);
  const float2 win  = *reinterpret_cast<const float2*>(W_in + (size_t)row * I + 2 * lane);

  // ---- publish slot 0 = zeros tagged base (2 lines per block) ----
  if (tid < M)
    __hip_atomic_store(&g_hy[(size_t)h * M + tid], pack(0.0f, base),
                       __ATOMIC_RELAXED, __HIP_MEMORY_SCOPE_AGENT);
  float hz = 0.f;

  // x[0] prefetch (per-lane slice; same for every wave)
  float2 xd = *reinterpret_cast<const float2*>(x + 2 * lane);

  const int hcol = tid >> 2;            // column this thread stages
  const int moff = (tid & 3) * 4;       // its 4 modules of that column

  for (int t = 0; t < T; ++t) {
    const bool last = (t == T - 1);
    const int  cur  = t & 1;

    // ---- poll own 4 packed values of slot t; tag match = data ready ----
    {
      const unsigned int tgt = base + (unsigned int)t;
      const u64* src = g_hy + (size_t)t * NROW + hcol * M + moff;
      u64 v0 = __hip_atomic_load(src + 0, __ATOMIC_RELAXED, __HIP_MEMORY_SCOPE_AGENT);
      u64 v1 = __hip_atomic_load(src + 1, __ATOMIC_RELAXED, __HIP_MEMORY_SCOPE_AGENT);
      u64 v2 = __hip_atomic_load(src + 2, __ATOMIC_RELAXED, __HIP_MEMORY_SCOPE_AGENT);
      u64 v3 = __hip_atomic_load(src + 3, __ATOMIC_RELAXED, __HIP_MEMORY_SCOPE_AGENT);
      while ((unsigned int)v0 != tgt)
        v0 = __hip_atomic_load(src + 0, __ATOMIC_RELAXED, __HIP_MEMORY_SCOPE_AGENT);
      while ((unsigned int)v1 != tgt)
        v1 = __hip_atomic_load(src + 1, __ATOMIC_RELAXED, __HIP_MEMORY_SCOPE_AGENT);
      while ((unsigned int)v2 != tgt)
        v2 = __hip_atomic_load(src + 2, __ATOMIC_RELAXED, __HIP_MEMORY_SCOPE_AGENT);
      while ((unsigned int)v3 != tgt)
        v3 = __hip_atomic_load(src + 3, __ATOMIC_RELAXED, __HIP_MEMORY_SCOPE_AGENT);
      hy_lds[cur][(moff + 0) * HP + hcol] = __uint_as_float((unsigned int)(v0 >> 32));
      hy_lds[cur][(moff + 1) * HP + hcol] = __uint_as_float((unsigned int)(v1 >> 32));
      hy_lds[cur][(moff + 2) * HP + hcol] = __uint_as_float((unsigned int)(v2 >> 32));
      hy_lds[cur][(moff + 3) * HP + hcol] = __uint_as_float((unsigned int)(v3 >> 32));
    }
    __syncthreads();   // the ONLY barrier per step

    // input term (xd prefetched last iteration)
    float acc_o = win.x * (maskm * xd.x);
    acc_o = fmaf(win.y, maskm * xd.y, acc_o);
    // recurrent term
    {
      const f32x4 hp = *reinterpret_cast<const f32x4*>(&hy_lds[cur][m * HP + 4 * lane]);
      acc_o = fmaf(wrec.x, hp.x, acc_o);
      acc_o = fmaf(wrec.y, hp.y, acc_o);
      acc_o = fmaf(wrec.z, hp.z, acc_o);
      acc_o = fmaf(wrec.w, hp.w, acc_o);
    }
    // feedback: register weights x LDS hy fragments
    float acc_fb = 0.f;
#pragma unroll
    for (int k = 0; k < M; ++k) {
      if (k < ocnt) {
        const int o = s_olist[m][k];
        const f32x4 hp = *reinterpret_cast<const f32x4*>(&hy_lds[cur][o * HP + 4 * lane]);
        float po = wreg[k].x * hp.x;
        po = fmaf(wreg[k].y, hp.y, po);
        po = fmaf(wreg[k].z, hp.z, po);
        po = fmaf(wreg[k].w, hp.w, po);
        acc_fb += po;
      }
    }

    // wave-wide butterfly reduce
    for (int off = 32; off > 0; off >>= 1) {
      acc_fb += __shfl_xor(acc_fb, off);
      acc_o  += __shfl_xor(acc_o,  off);
    }

    if (lane == 0) {
      const float fb   = scal * acc_fb;
      const float hy_p = hy_lds[cur][m * HP + h];
      const float pre  = acc_o + biasv + fb;
      const float hz_n = hz + DT_C * (tanhf(pre) - GAMMA_C * hy_p - EPS_C * hz);
      const float hy_n = hy_p + DT_C * hz_n;
      hz = hz_n;
      // publish: ONE u64 (value+tag) — the signal IS the data
      if (!last)
        __hip_atomic_store(&g_hy[(size_t)(t + 1) * NROW + h * M + m],
                           pack(hy_n, base + (unsigned int)t + 1u),
                           __ATOMIC_RELAXED, __HIP_MEMORY_SCOPE_AGENT);
      outb_hz[t][m] = hz_n;
      outb_fb[t][m] = fb;
      if (last)   // keep slot T consistent for the flush below
        __hip_atomic_store(&g_hy[(size_t)T * NROW + h * M + m],
                           pack(hy_n, base + (unsigned int)T),
                           __ATOMIC_RELAXED, __HIP_MEMORY_SCOPE_AGENT);
    }

    if (!last)
      xd = *reinterpret_cast<const float2*>(x + (size_t)(t + 1) * I + 2 * lane);
  }

  __syncthreads();   // outb_* complete

  // ---- one-time flush: hy from own g_hy slots, hz/fb from LDS ----
  const size_t fb_base = (size_t)T * M * 2 * H;
  for (int i = tid; i < T * M; i += NTHR) {
    const int t  = i >> 4;
    const int mm = i & 15;
    const u64 v = __hip_atomic_load(&g_hy[(size_t)(t + 1) * NROW + h * M + mm],
                                    __ATOMIC_RELAXED, __HIP_MEMORY_SCOPE_AGENT);
    const float hyv = __uint_as_float((unsigned int)(v >> 32));
    const size_t so = (size_t)t * (M * 2 * H) + (size_t)mm * (2 * H);
    out[so + h]     = hyv;
    out[so + H + h] = outb_hz[t][mm];
    out[fb_base + (size_t)t * (M * H) + (size_t)mm * H + h] = outb_fb[t][mm];
  }

  // ---- advance epoch once per launch (block 0, after all its work) ----
  __syncthreads();
  if (h == 0 && tid == 0)
    __hip_atomic_fetch_add(&g_epoch, (unsigned int)T, __ATOMIC_ACQ_REL,
                           __HIP_MEMORY_SCOPE_AGENT);
}

extern "C" void kernel_launch(void* const* d_in, const int* in_sizes, int n_in,
                              void* d_out, int out_size, void* d_ws, size_t ws_size,
                              hipStream_t stream) {
  const float* x     = (const float*)d_in[0];
  const float* wm    = (const float*)d_in[1];
  const float* conn  = (const float*)d_in[2];
  const float* mask  = (const float*)d_in[3];
  const float* W_in  = (const float*)d_in[4];
  const float* W_rec = (const float*)d_in[5];
  const float* bias  = (const float*)d_in[6];

  rnn_persistent<<<NBLK, NTHR, 0, stream>>>(
      x, wm, conn, mask, W_in, W_rec, bias, (float*)d_out);
}

// Round 9
// 2361.417 us; speedup vs baseline: 1.4784x; 1.4784x over previous
//
#include <hip/hip_runtime.h>
#include <math.h>

// Archetipes RNN scan: T=256 sequential steps, M=16 modules, H=256, I=128.
// R9 = R7 structure (best so far, 2265 us) with the poller-flood removed.
// R8 post-mortem: 262k pollers on data lines -> FETCH 49->261 MB, retries
// congest the fabric the awaited stores traverse. Polls consume LLC/fabric
// BW ~ pollers x lines. R7 itself had 1024 pollers/block on 16 flag lines.
// Changes vs R7:
//  1. Wave-0-only polling: lane i checks flags 4i..4i+3 (2 u64 loads) with
//     __all ballot -> 64 pollers/block (16k total, was 262k). One extra
//     __syncthreads per step (3 total) - cheap vs the flood.
//  2. Conflict-free transpose, no pad: thread stages column hcol=tid&255,
//     modules m0=(tid>>8)*4. Within a wave hcol=64c+j -> LDS write bank =
//     j&31 = 2-way (free, m136). R7/R8 indexing was 4-way (25.2M/8.5M
//     conflict counts).
// Invariants (validated R6/R7): write-through agent data stores drained by
// __syncthreads, then RELEASE flag store; relaxed polls; LLC-direct agent
// staging loads; per-producer monotone flags (+T per launch, base re-read
// at entry -> graph-replay safe); g_hy slots written once per launch.
// Weights register/AGPR-resident (R3). Outputs buffered in LDS, one flush.

#define DT_C    0.042f
#define GAMMA_C 2.7f
#define EPS_C   4.7f

constexpr int M = 16, H = 256, I = 128, T = 256;
constexpr int NROW = M * H;   // 4096
constexpr int NBLK = 256;
constexpr int NTHR = 1024;    // 16 waves

typedef float f32x4 __attribute__((ext_vector_type(4)));
typedef unsigned long long u64;

// Slot s = hy after s steps, layout [s][h][m] (64 B per (s,h) -> one-line
// publish per block). Written once per launch, bitwise-identical across
// replays.
__device__ __align__(64) float g_hy[(size_t)(T + 1) * NROW];
__device__ __align__(16) unsigned int g_step[NBLK];   // per-producer flags

__global__ __launch_bounds__(NTHR) void rnn_persistent(
    const float* __restrict__ x,      // T*I
    const float* __restrict__ wm,     // M*M*H*H
    const float* __restrict__ conn,   // M*M
    const float* __restrict__ mask,   // M
    const float* __restrict__ W_in,   // M*H*I
    const float* __restrict__ W_rec,  // M*H*H
    const float* __restrict__ bias,   // M*H
    float* __restrict__ out)          // T*M*2*H state_seq, then T*M*H fb_seq
{
  const int h    = blockIdx.x;
  const int tid  = threadIdx.x;
  const int m    = tid >> 6;      // wave = module
  const int lane = tid & 63;

  __shared__ float hy_lds[NROW];        // 16 KB, layout [m][h], no pad
  __shared__ float outb_hz[T][M];       // 16 KB
  __shared__ float outb_fb[T][M];       // 16 KB
  __shared__ float s_c[M * M];
  __shared__ float s_scal[M];
  __shared__ int   s_olist[M][M];
  __shared__ float s_oc[M][M];
  __shared__ int   s_ocnt[M];
  __shared__ unsigned int s_base;

  if (tid == 0)
    s_base = __hip_atomic_load(&g_step[h], __ATOMIC_RELAXED, __HIP_MEMORY_SCOPE_AGENT);
  if (tid < M * M) s_c[tid] = conn[tid];
  __syncthreads();
  if (tid < M) {
    float s = 0.f; int cnt = 0;
    for (int o = 0; o < M; ++o) {
      float c = s_c[tid * M + o];
      s += c;
      if (c != 0.f) { s_olist[tid][cnt] = o; s_oc[tid][cnt] = c; ++cnt; }
    }
    for (int k = cnt; k < M; ++k) { s_olist[tid][k] = 0; s_oc[tid][k] = 0.f; }
    s_ocnt[tid] = cnt;
    s_scal[tid] = 1.0f / fmaxf(s, 1.0f);
  }
  __syncthreads();

  const int   row   = m * H + h;
  const float maskm = mask[m];
  const float biasv = bias[row];
  const float scal  = s_scal[m];
  const int   ocnt  = s_ocnt[m];
  const unsigned int base = s_base;

  // ---- one-time: weights into registers (conn pre-applied) ----
  f32x4 wreg[M];
#pragma unroll
  for (int k = 0; k < M; ++k) {
    if (k < ocnt) {
      const int o = s_olist[m][k];
      const f32x4 wv = *reinterpret_cast<const f32x4*>(
          wm + ((size_t)(m * M + o) * H + h) * H + 4 * lane);
      wreg[k] = wv * s_oc[m][k];
    } else {
      wreg[k] = (f32x4)0.f;
    }
  }
  const f32x4  wrec = *reinterpret_cast<const f32x4*>(W_rec + (size_t)row * H + 4 * lane);
  const float2 win  = *reinterpret_cast<const float2*>(W_in + (size_t)row * I + 2 * lane);

  // ---- publish slot 0 = zeros (one 64-B line per block) ----
  if (tid < M)
    __hip_atomic_store(&g_hy[(size_t)h * M + tid], 0.0f,
                       __ATOMIC_RELAXED, __HIP_MEMORY_SCOPE_AGENT);
  float hz = 0.f;
  __syncthreads();   // vmcnt(0): zero line drained
  if (tid == 0)
    __hip_atomic_store(&g_step[h], base + 1u, __ATOMIC_RELEASE, __HIP_MEMORY_SCOPE_AGENT);

  // x[0] prefetch (per-lane slice; same for every wave)
  float2 xd = *reinterpret_cast<const float2*>(x + 2 * lane);

  const int hcol = tid & 255;           // column this thread stages
  const int m0   = (tid >> 8) << 2;     // its 4 modules of that column

  for (int t = 0; t < T; ++t) {
    const bool last = (t == T - 1);

    // ---- wave 0 polls all 256 flags (64 pollers, ballot exit) ----
    if (tid < 64) {
      const unsigned int tgt = base + (unsigned int)t + 1u;
      const u64* fp = reinterpret_cast<const u64*>(g_step) + 2 * tid;
      for (;;) {
        u64 a = __hip_atomic_load(fp,     __ATOMIC_RELAXED, __HIP_MEMORY_SCOPE_AGENT);
        u64 b = __hip_atomic_load(fp + 1, __ATOMIC_RELAXED, __HIP_MEMORY_SCOPE_AGENT);
        bool ok = ((unsigned int)a >= tgt) & ((unsigned int)(a >> 32) >= tgt) &
                  ((unsigned int)b >= tgt) & ((unsigned int)(b >> 32) >= tgt);
        if (__all(ok)) break;
        __builtin_amdgcn_s_sleep(1);
      }
    }
    __syncthreads();

    // ---- stage slot t -> LDS[m][h]; wave-stride-1 columns -> 2-way banks
    {
      const u64* src = reinterpret_cast<const u64*>(
          g_hy + (size_t)t * NROW + hcol * M + m0);
      u64 a = __hip_atomic_load(src,     __ATOMIC_RELAXED, __HIP_MEMORY_SCOPE_AGENT);
      u64 b = __hip_atomic_load(src + 1, __ATOMIC_RELAXED, __HIP_MEMORY_SCOPE_AGENT);
      union { u64 q[2]; float f[4]; } u; u.q[0] = a; u.q[1] = b;
      hy_lds[(m0 + 0) * H + hcol] = u.f[0];
      hy_lds[(m0 + 1) * H + hcol] = u.f[1];
      hy_lds[(m0 + 2) * H + hcol] = u.f[2];
      hy_lds[(m0 + 3) * H + hcol] = u.f[3];
    }
    __syncthreads();

    // input term (xd prefetched last iteration)
    float acc_o = win.x * (maskm * xd.x);
    acc_o = fmaf(win.y, maskm * xd.y, acc_o);
    // recurrent term
    {
      const f32x4 hp = *reinterpret_cast<const f32x4*>(&hy_lds[m * H + 4 * lane]);
      acc_o = fmaf(wrec.x, hp.x, acc_o);
      acc_o = fmaf(wrec.y, hp.y, acc_o);
      acc_o = fmaf(wrec.z, hp.z, acc_o);
      acc_o = fmaf(wrec.w, hp.w, acc_o);
    }
    // feedback: register weights x LDS hy fragments
    float acc_fb = 0.f;
#pragma unroll
    for (int k = 0; k < M; ++k) {
      if (k < ocnt) {
        const int o = s_olist[m][k];
        const f32x4 hp = *reinterpret_cast<const f32x4*>(&hy_lds[o * H + 4 * lane]);
        float po = wreg[k].x * hp.x;
        po = fmaf(wreg[k].y, hp.y, po);
        po = fmaf(wreg[k].z, hp.z, po);
        po = fmaf(wreg[k].w, hp.w, po);
        acc_fb += po;
      }
    }

    // wave-wide butterfly reduce
    for (int off = 32; off > 0; off >>= 1) {
      acc_fb += __shfl_xor(acc_fb, off);
      acc_o  += __shfl_xor(acc_o,  off);
    }

    if (lane == 0) {
      const float fb   = scal * acc_fb;
      const float hy_p = hy_lds[m * H + h];
      const float pre  = acc_o + biasv + fb;
      const float hz_n = hz + DT_C * (tanhf(pre) - GAMMA_C * hy_p - EPS_C * hz);
      const float hy_n = hy_p + DT_C * hz_n;
      hz = hz_n;
      // publish hy_t into slot t+1: 16 waves' stores hit ONE 64-B line
      __hip_atomic_store(&g_hy[(size_t)(t + 1) * NROW + h * M + m], hy_n,
                         __ATOMIC_RELAXED, __HIP_MEMORY_SCOPE_AGENT);
      outb_hz[t][m] = hz_n;
      outb_fb[t][m] = fb;
    }

    __syncthreads();   // vmcnt(0): the single publish line drained

    if (tid == 0 && !last)
      __hip_atomic_store(&g_step[h], base + (unsigned int)t + 2u,
                         __ATOMIC_RELEASE, __HIP_MEMORY_SCOPE_AGENT);

    if (!last)
      xd = *reinterpret_cast<const float2*>(x + (size_t)(t + 1) * I + 2 * lane);
  }

  // ---- one-time flush: hy from own g_hy slots, hz/fb from LDS ----
  const size_t fb_base = (size_t)T * M * 2 * H;
  for (int i = tid; i < T * M; i += NTHR) {
    const int t  = i >> 4;
    const int mm = i & 15;
    const float hyv = __hip_atomic_load(&g_hy[(size_t)(t + 1) * NROW + h * M + mm],
                                        __ATOMIC_RELAXED, __HIP_MEMORY_SCOPE_AGENT);
    const size_t so = (size_t)t * (M * 2 * H) + (size_t)mm * (2 * H);
    out[so + h]     = hyv;
    out[so + H + h] = outb_hz[t][mm];
    out[fb_base + (size_t)t * (M * H) + (size_t)mm * H + h] = outb_fb[t][mm];
  }
}

extern "C" void kernel_launch(void* const* d_in, const int* in_sizes, int n_in,
                              void* d_out, int out_size, void* d_ws, size_t ws_size,
                              hipStream_t stream) {
  const float* x     = (const float*)d_in[0];
  const float* wm    = (const float*)d_in[1];
  const float* conn  = (const float*)d_in[2];
  const float* mask  = (const float*)d_in[3];
  const float* W_in  = (const float*)d_in[4];
  const float* W_rec = (const float*)d_in[5];
  const float* bias  = (const float*)d_in[6];

  rnn_persistent<<<NBLK, NTHR, 0, stream>>>(
      x, wm, conn, mask, W_in, W_rec, bias, (float*)d_out);
}